// Round 15
// baseline (230.620 us; speedup 1.0000x reference)
//
#include <hip/hip_runtime.h>
#include <hip/hip_fp16.h>

#define NN 50000
#define NE 1250000
#define NE4 312500
#define NG 256
#define NBKT 782          // ceil(NN/64) buckets of 64 nodes
#define BCAP 2048         // fixed per-bucket capacity (avg ~1600, P[>2048]~1e-26)
#define TILE 4096         // edges per scatter block
#define NTB 306           // ceil(NE/TILE)
#define NWAVE 8192        // occupancy-packed wave count for k_edge (1024 SIMDs x 8)

#define QSCALE 0.18033688011112042f   // log2(e)/8
#define EXP2 __builtin_amdgcn_exp2f

#if defined(__has_builtin)
#  if __has_builtin(__builtin_amdgcn_fdot2)
#    define HAS_FDOT2 1
#  endif
#endif

typedef _Float16 h2vec __attribute__((ext_vector_type(2)));

static __device__ __forceinline__ float fdot2f(unsigned a, unsigned b, float c) {
#ifdef HAS_FDOT2
    return __builtin_amdgcn_fdot2(__builtin_bit_cast(h2vec, a),
                                  __builtin_bit_cast(h2vec, b), c, false);
#else
    float2 fa = __half22float2(__builtin_bit_cast(__half2, a));
    float2 fb = __half22float2(__builtin_bit_cast(__half2, b));
    return fmaf(fa.x, fb.x, fmaf(fa.y, fb.y, c));
#endif
}

static __device__ __forceinline__ unsigned h2u(__half2 h) {
    return __builtin_bit_cast(unsigned, h);
}

// ---------- zero the bucket cursors ----------
__global__ void k_zero(int* __restrict__ gCursor) {
    int i = blockIdx.x * 256 + threadIdx.x;
    if (i < NBKT) gCursor[i] = 0;
}

// ---------- multisplit scatter: 4B records into fixed 2048-slot bucket regions ----------
// rec = src(16) | dloc(6)<<16 | ew10(10)<<22
__global__ void k_bscatter(const int* __restrict__ src, const int* __restrict__ dst,
                           const float* __restrict__ ew, int* __restrict__ gCursor,
                           unsigned* __restrict__ bbuf) {
    __shared__ int cnt[NBKT];
    __shared__ int base[NBKT];
    for (int i = threadIdx.x; i < NBKT; i += 256) cnt[i] = 0;
    __syncthreads();
    const int4* s4 = (const int4*)src;
    const int4* d4 = (const int4*)dst;
    const float4* w4 = (const float4*)ew;
    int b4 = blockIdx.x * (TILE / 4);
    unsigned rec[16]; int bkt[16];
    #pragma unroll
    for (int j = 0; j < 4; j++) {
        int i4 = b4 + j * 256 + threadIdx.x;
        if (i4 < NE4) {
            int4 s = s4[i4]; int4 d = d4[i4]; float4 w = w4[i4];
            int b0 = d.x >> 6, b1 = d.y >> 6, b2 = d.z >> 6, b3 = d.w >> 6;
            bkt[4*j+0] = b0; bkt[4*j+1] = b1; bkt[4*j+2] = b2; bkt[4*j+3] = b3;
            rec[4*j+0] = (unsigned)s.x | ((unsigned)(d.x & 63) << 16) | ((unsigned)(w.x * 1023.f + 0.5f) << 22);
            rec[4*j+1] = (unsigned)s.y | ((unsigned)(d.y & 63) << 16) | ((unsigned)(w.y * 1023.f + 0.5f) << 22);
            rec[4*j+2] = (unsigned)s.z | ((unsigned)(d.z & 63) << 16) | ((unsigned)(w.z * 1023.f + 0.5f) << 22);
            rec[4*j+3] = (unsigned)s.w | ((unsigned)(d.w & 63) << 16) | ((unsigned)(w.w * 1023.f + 0.5f) << 22);
            atomicAdd(&cnt[b0], 1); atomicAdd(&cnt[b1], 1);
            atomicAdd(&cnt[b2], 1); atomicAdd(&cnt[b3], 1);
        } else {
            bkt[4*j+0] = -1; bkt[4*j+1] = -1; bkt[4*j+2] = -1; bkt[4*j+3] = -1;
        }
    }
    __syncthreads();
    for (int i = threadIdx.x; i < NBKT; i += 256)
        base[i] = cnt[i] ? (i << 11) + atomicAdd(&gCursor[i], cnt[i]) : 0;
    __syncthreads();
    #pragma unroll
    for (int j = 0; j < 16; j++) {
        if (bkt[j] >= 0) {
            int pos = atomicAdd(&base[bkt[j]], 1);
            if (pos < ((bkt[j] + 1) << 11)) bbuf[pos] = rec[j];   // overflow clamp (never in practice)
        }
    }
}

// ---------- per-bucket sort into final CSR; emits off + deg ----------
__global__ void k_bsort(const int* __restrict__ gCursor, const unsigned* __restrict__ bbuf,
                        int* __restrict__ off, int* __restrict__ deg,
                        unsigned* __restrict__ pairP) {
    int b = blockIdx.x;
    int st = b << 11;
    int ce = gCursor[b]; if (ce > BCAP) ce = BCAP;
    __shared__ unsigned sbuf[BCAP];   // 8KB
    __shared__ int h[64];
    __shared__ int cur[64];
    if (threadIdx.x < 64) h[threadIdx.x] = 0;
    __syncthreads();
    for (int i = threadIdx.x; i < ce; i += 256) {
        unsigned r = bbuf[st + i];
        sbuf[i] = r;
        atomicAdd(&h[(r >> 16) & 63], 1);
    }
    __syncthreads();
    if (threadIdx.x < 64) {
        int v = h[threadIdx.x];
        int inc = v;
        #pragma unroll
        for (int o = 1; o < 64; o <<= 1) {
            int tmp = __shfl_up(inc, o);
            if (threadIdx.x >= o) inc += tmp;
        }
        int exc = st + inc - v;
        cur[threadIdx.x] = exc;
        int n = b * 64 + threadIdx.x;
        if (n < NN) { off[n] = exc; deg[n] = v; }
    }
    __syncthreads();
    for (int i = threadIdx.x; i < ce; i += 256) {
        unsigned r = sbuf[i];
        int pos = atomicAdd(&cur[(r >> 16) & 63], 1);
        float w = (float)(r >> 22) * (1.f / 1023.f);
        unsigned hw = (unsigned)__half_as_ushort(__float2half(w));
        pairP[pos] = (r & 0xFFFFu) | (hw << 16);
    }
}

// ---------- fused node linear: wave = matrix (0=q,1=k,2=v,3=s), W col in VGPRs ----------
// LDS-staged x (16 nodes/tile, float4) with next-tile register prefetch; 4 indep accumulators.
// q written fp16 pre-scaled by log2(e)/8; kv row = [64 k-halfs][64 v-halfs]; agg f32.
__global__ __launch_bounds__(256, 4)
void k_linear(const float* __restrict__ xin,
              const float* __restrict__ Wq, const float* __restrict__ bq,
              const float* __restrict__ Wk, const float* __restrict__ bk,
              const float* __restrict__ Wv, const float* __restrict__ bv,
              const float* __restrict__ Ws, const float* __restrict__ bs,
              __half* __restrict__ qh, __half* __restrict__ kvh,
              float* __restrict__ agg) {
    int tid = threadIdx.x;
    int mat = tid >> 6, feat = tid & 63;
    const float* W = mat == 0 ? Wq : mat == 1 ? Wk : mat == 2 ? Wv : Ws;
    const float* b = mat == 0 ? bq : mat == 1 ? bk : mat == 2 ? bv : bs;

    float wcol[64];
    #pragma unroll
    for (int k = 0; k < 64; k++) wcol[k] = W[k * 64 + feat];
    float bias = b[feat];
    int kvoff = feat + (mat == 2 ? 64 : 0);

    __shared__ __align__(16) float sx[16 * 64];
    const float4* x4 = (const float4*)xin;

    int n0 = blockIdx.x * 16;
    if (n0 >= NN) return;
    float4 nxt = x4[n0 * 16 + tid];
    int stride = gridDim.x * 16;

    for (; n0 < NN; n0 += stride) {
        __syncthreads();
        ((float4*)sx)[tid] = nxt;
        __syncthreads();
        int n1 = n0 + stride;
        if (n1 < NN) nxt = x4[n1 * 16 + tid];   // prefetch next tile under compute
        for (int c = 0; c < 16; c++) {
            const float4* sxc = (const float4*)(sx + c * 64);
            float a0 = bias, a1 = 0.f, a2 = 0.f, a3 = 0.f;
            #pragma unroll
            for (int k4 = 0; k4 < 16; k4 += 4) {
                float4 v0 = sxc[k4 + 0], v1 = sxc[k4 + 1];
                float4 v2 = sxc[k4 + 2], v3 = sxc[k4 + 3];
                a0 = fmaf(v0.x, wcol[4 * k4 + 0], a0);
                a0 = fmaf(v0.y, wcol[4 * k4 + 1], a0);
                a0 = fmaf(v0.z, wcol[4 * k4 + 2], a0);
                a0 = fmaf(v0.w, wcol[4 * k4 + 3], a0);
                a1 = fmaf(v1.x, wcol[4 * k4 + 4], a1);
                a1 = fmaf(v1.y, wcol[4 * k4 + 5], a1);
                a1 = fmaf(v1.z, wcol[4 * k4 + 6], a1);
                a1 = fmaf(v1.w, wcol[4 * k4 + 7], a1);
                a2 = fmaf(v2.x, wcol[4 * k4 + 8], a2);
                a2 = fmaf(v2.y, wcol[4 * k4 + 9], a2);
                a2 = fmaf(v2.z, wcol[4 * k4 + 10], a2);
                a2 = fmaf(v2.w, wcol[4 * k4 + 11], a2);
                a3 = fmaf(v3.x, wcol[4 * k4 + 12], a3);
                a3 = fmaf(v3.y, wcol[4 * k4 + 13], a3);
                a3 = fmaf(v3.z, wcol[4 * k4 + 14], a3);
                a3 = fmaf(v3.w, wcol[4 * k4 + 15], a3);
            }
            float acc = (a0 + a1) + (a2 + a3);
            int nn = n0 + c;
            if (mat == 0)      qh[nn * 64 + feat] = __float2half(acc * QSCALE);
            else if (mat == 3) agg[nn * 64 + feat] = acc;
            else               kvh[nn * 128 + kvoff] = __float2half(acc);
        }
    }
}

// ---------- fused edge kernel: occupancy-packed grid-stride, wave per node ----------
// 8-lane groups, fdot2, no-max softmax; stores relu(skip + attn) to outp[node row]
__global__ void k_edge(const unsigned* __restrict__ pairP, const int* __restrict__ off,
                       const int* __restrict__ deg,
                       const __half* __restrict__ qh, const uint4* __restrict__ kv16,
                       const float* __restrict__ We, const float* __restrict__ aggin,
                       float* __restrict__ outp) {
    int wid = blockIdx.x * 4 + (threadIdx.x >> 6);   // wave id, 0..NWAVE-1
    int lane = threadIdx.x & 63;
    int g = lane >> 3, l = lane & 7;   // 8 groups x 8 lanes

    const float4* wp = (const float4*)(We + l * 8);
    float4 wa = wp[0], wb = wp[1];
    unsigned we01 = h2u(__floats2half2_rn(wa.x, wa.y));
    unsigned we23 = h2u(__floats2half2_rn(wa.z, wa.w));
    unsigned we45 = h2u(__floats2half2_rn(wb.x, wb.y));
    unsigned we67 = h2u(__floats2half2_rn(wb.z, wb.w));
    const uint4* q4 = (const uint4*)qh;

    for (int n = wid; n < NN; n += NWAVE) {
        uint4 qu = q4[n * 8 + l];      // 8 fp16 q feats (pre-scaled by log2e/8)
        int st = off[n], dg = deg[n];

        float qwe = fdot2f(qu.x, we01, fdot2f(qu.y, we23,
                    fdot2f(qu.z, we45, fdot2f(qu.w, we67, 0.f))));
        qwe += __shfl_xor(qwe, 1); qwe += __shfl_xor(qwe, 2); qwe += __shfl_xor(qwe, 4);

        float den = 0.f, sw = 0.f;
        float acc[8] = {0.f, 0.f, 0.f, 0.f, 0.f, 0.f, 0.f, 0.f};

        auto edge = [&](unsigned pr, uint4 kk, uint4 vv) {
            float w = __half2float(__ushort_as_half((unsigned short)(pr >> 16)));
            float tA = fdot2f(qu.x, kk.x, fdot2f(qu.y, kk.y, 0.f));
            float tB = fdot2f(qu.z, kk.z, fdot2f(qu.w, kk.w, 0.f));
            float t = tA + tB;
            t += __shfl_xor(t, 1); t += __shfl_xor(t, 2); t += __shfl_xor(t, 4);
            t = fmaf(w, qwe, t);
            float p = EXP2(t);        // shift-invariant softmax, |t| << 127
            den += p;
            sw = fmaf(p, w, sw);
            float2 v0 = __half22float2(__builtin_bit_cast(__half2, vv.x));
            float2 v1 = __half22float2(__builtin_bit_cast(__half2, vv.y));
            float2 v2 = __half22float2(__builtin_bit_cast(__half2, vv.z));
            float2 v3 = __half22float2(__builtin_bit_cast(__half2, vv.w));
            acc[0] = fmaf(p, v0.x, acc[0]); acc[1] = fmaf(p, v0.y, acc[1]);
            acc[2] = fmaf(p, v1.x, acc[2]); acc[3] = fmaf(p, v1.y, acc[3]);
            acc[4] = fmaf(p, v2.x, acc[4]); acc[5] = fmaf(p, v2.y, acc[5]);
            acc[6] = fmaf(p, v3.x, acc[6]); acc[7] = fmaf(p, v3.y, acc[7]);
        };

        int nfull = dg >> 3;
        if (nfull > 0) {
            unsigned prA = pairP[st + g];
            unsigned prB = (nfull > 1) ? pairP[st + 8 + g] : 0u;
            unsigned rowA = prA & 0xFFFFu;
            uint4 kkA = kv16[rowA * 16 + l];
            uint4 vvA = kv16[rowA * 16 + 8 + l];
            for (int i = 0; i + 1 < nfull; i++) {
                unsigned prC = (i + 2 < nfull) ? pairP[st + (i + 2) * 8 + g] : 0u;
                unsigned rowB = prB & 0xFFFFu;
                uint4 kkB = kv16[rowB * 16 + l];
                uint4 vvB = kv16[rowB * 16 + 8 + l];
                edge(prA, kkA, vvA);
                prA = prB; kkA = kkB; vvA = vvB; prB = prC;
            }
            edge(prA, kkA, vvA);
        }
        int tl = nfull * 8 + g;
        if (tl < dg) {
            unsigned pr = pairP[st + tl];
            unsigned row = pr & 0xFFFFu;
            uint4 kk = kv16[row * 16 + l];
            uint4 vv = kv16[row * 16 + 8 + l];
            edge(pr, kk, vv);
        }

        // merge the 8 group states (pure adds)
        #pragma unroll
        for (int o = 8; o <= 32; o <<= 1) {
            den += __shfl_xor(den, o);
            sw  += __shfl_xor(sw, o);
            #pragma unroll
            for (int j = 0; j < 8; j++) acc[j] += __shfl_xor(acc[j], o);
        }

        if (g == 0) {
            float inv = 1.f / fmaxf(den, 1e-16f);
            float swi = sw * inv;
            const float4* ain = (const float4*)(aggin + n * 64 + l * 8);
            float4 a0 = ain[0], a1 = ain[1];
            a0.x = fmaxf(fmaf(acc[0], inv, fmaf(swi, wa.x, a0.x)), 0.f);
            a0.y = fmaxf(fmaf(acc[1], inv, fmaf(swi, wa.y, a0.y)), 0.f);
            a0.z = fmaxf(fmaf(acc[2], inv, fmaf(swi, wa.z, a0.z)), 0.f);
            a0.w = fmaxf(fmaf(acc[3], inv, fmaf(swi, wa.w, a0.w)), 0.f);
            a1.x = fmaxf(fmaf(acc[4], inv, fmaf(swi, wb.x, a1.x)), 0.f);
            a1.y = fmaxf(fmaf(acc[5], inv, fmaf(swi, wb.y, a1.y)), 0.f);
            a1.z = fmaxf(fmaf(acc[6], inv, fmaf(swi, wb.z, a1.z)), 0.f);
            a1.w = fmaxf(fmaf(acc[7], inv, fmaf(swi, wb.w, a1.w)), 0.f);
            float4* ao = (float4*)(outp + n * 64 + l * 8);
            ao[0] = a0; ao[1] = a1;
        }
    }
}

// ---------- pool + head: block per graph, batch is sorted ----------
__global__ void k_final(const float* __restrict__ h, const int* __restrict__ batch,
                        const float* __restrict__ Wl, const float* __restrict__ bl,
                        float* __restrict__ out) {
    int g = blockIdx.x;
    int tid = threadIdx.x;
    int lo = 0, hi = NN;
    while (lo < hi) { int mid = (lo + hi) >> 1; if (batch[mid] < g) lo = mid + 1; else hi = mid; }
    int s0 = lo;
    hi = NN;
    while (lo < hi) { int mid = (lo + hi) >> 1; if (batch[mid] < g + 1) lo = mid + 1; else hi = mid; }
    int s1 = lo;

    int sub = tid >> 6, lane = tid & 63;
    float a = 0.f;
    for (int n = s0 + sub; n < s1; n += 4) a += h[n * 64 + lane];   // h already relu'd
    __shared__ float sred[4][64];
    sred[sub][lane] = a;
    __syncthreads();
    if (tid < 64) {
        float p = (sred[0][tid] + sred[1][tid] + sred[2][tid] + sred[3][tid])
                  / fmaxf((float)(s1 - s0), 1.f);
        float a0 = p * Wl[tid * 2 + 0];
        float a1 = p * Wl[tid * 2 + 1];
        #pragma unroll
        for (int o = 1; o < 64; o <<= 1) { a0 += __shfl_xor(a0, o); a1 += __shfl_xor(a1, o); }
        if (tid == 0) { out[g * 2 + 0] = a0 + bl[0]; out[g * 2 + 1] = a1 + bl[1]; }
    }
}

extern "C" void kernel_launch(void* const* d_in, const int* in_sizes, int n_in,
                              void* d_out, int out_size, void* d_ws, size_t ws_size,
                              hipStream_t stream) {
    const float* x    = (const float*)d_in[0];
    const int*   ei   = (const int*)d_in[1];
    const float* ew   = (const float*)d_in[2];
    const int*   batch= (const int*)d_in[3];
    const float *Wq1 = (const float*)d_in[4],  *bq1 = (const float*)d_in[5],
                *Wk1 = (const float*)d_in[6],  *bk1 = (const float*)d_in[7],
                *Wv1 = (const float*)d_in[8],  *bv1 = (const float*)d_in[9],
                *We1 = (const float*)d_in[10], *Ws1 = (const float*)d_in[11],
                *bs1 = (const float*)d_in[12],
                *Wq2 = (const float*)d_in[13], *bq2 = (const float*)d_in[14],
                *Wk2 = (const float*)d_in[15], *bk2 = (const float*)d_in[16],
                *Wv2 = (const float*)d_in[17], *bv2 = (const float*)d_in[18],
                *We2 = (const float*)d_in[19], *Ws2 = (const float*)d_in[20],
                *bs2 = (const float*)d_in[21],
                *Wl  = (const float*)d_in[22], *bl  = (const float*)d_in[23];
    const int* src = ei;        // edge_index[0]
    const int* dst = ei + NE;   // edge_index[1]
    float* out = (float*)d_out;

    float* p = (float*)d_ws;
    float* agg1 = p; p += (size_t)NN * 64;
    float* agg2 = p; p += (size_t)NN * 64;
    __half* qh  = (__half*)p; p += (size_t)NN * 32;   // NN*64 halfs
    __half* kvh = (__half*)p; p += (size_t)NN * 64;   // NN*128 halfs
    unsigned* bbuf  = (unsigned*)p; p += (size_t)NBKT * BCAP;
    unsigned* pairP = (unsigned*)p; p += (size_t)NBKT * BCAP;
    int* gCursor = (int*)p; p += NBKT;
    int* off     = (int*)p; p += NN;
    int* deg     = (int*)p; p += NN;

    dim3 b256(256);

    // ---- CSR build: zero cursors, multisplit scatter (fixed regions), per-bucket sort ----
    k_zero<<<4, b256, 0, stream>>>(gCursor);
    k_bscatter<<<NTB, b256, 0, stream>>>(src, dst, ew, gCursor, bbuf);
    k_bsort<<<NBKT, b256, 0, stream>>>(gCursor, bbuf, off, deg, pairP);

    // ---- layer 1 (k_edge stores relu'd h1 into agg1) ----
    k_linear<<<1024, b256, 0, stream>>>(x, Wq1, bq1, Wk1, bk1, Wv1, bv1, Ws1, bs1,
                                        qh, kvh, agg1);
    k_edge<<<NWAVE / 4, b256, 0, stream>>>(pairP, off, deg, qh, (const uint4*)kvh, We1,
                                           agg1, agg1);

    // ---- layer 2 ----
    k_linear<<<1024, b256, 0, stream>>>(agg1, Wq2, bq2, Wk2, bk2, Wv2, bv2, Ws2, bs2,
                                        qh, kvh, agg2);
    k_edge<<<NWAVE / 4, b256, 0, stream>>>(pairP, off, deg, qh, (const uint4*)kvh, We2,
                                           agg2, agg2);

    // ---- pool + head ----
    k_final<<<NG, b256, 0, stream>>>(agg2, batch, Wl, bl, out);
}

// Round 16
// 207.635 us; speedup vs baseline: 1.1107x; 1.1107x over previous
//
#include <hip/hip_runtime.h>
#include <hip/hip_fp16.h>

#define NN 50000
#define NE 1250000
#define NE4 312500
#define NG 256
#define NBKT 782          // ceil(NN/64) buckets of 64 nodes
#define BCAP 2048         // fixed per-bucket capacity (avg ~1600, P[>2048]~1e-26)
#define TILE 4096         // edges per scatter block
#define NTB 306           // ceil(NE/TILE)

#define QSCALE 0.18033688011112042f   // log2(e)/8
#define EXP2 __builtin_amdgcn_exp2f

#if defined(__has_builtin)
#  if __has_builtin(__builtin_amdgcn_fdot2)
#    define HAS_FDOT2 1
#  endif
#endif

typedef _Float16 h2vec __attribute__((ext_vector_type(2)));

static __device__ __forceinline__ float fdot2f(unsigned a, unsigned b, float c) {
#ifdef HAS_FDOT2
    return __builtin_amdgcn_fdot2(__builtin_bit_cast(h2vec, a),
                                  __builtin_bit_cast(h2vec, b), c, false);
#else
    float2 fa = __half22float2(__builtin_bit_cast(__half2, a));
    float2 fb = __half22float2(__builtin_bit_cast(__half2, b));
    return fmaf(fa.x, fb.x, fmaf(fa.y, fb.y, c));
#endif
}

static __device__ __forceinline__ unsigned h2u(__half2 h) {
    return __builtin_bit_cast(unsigned, h);
}

// ---------- zero the bucket cursors ----------
__global__ void k_zero(int* __restrict__ gCursor) {
    int i = blockIdx.x * 256 + threadIdx.x;
    if (i < NBKT) gCursor[i] = 0;
}

// ---------- multisplit scatter: 4B records into fixed 2048-slot bucket regions ----------
// rec = src(16) | dloc(6)<<16 | ew10(10)<<22
__global__ void k_bscatter(const int* __restrict__ src, const int* __restrict__ dst,
                           const float* __restrict__ ew, int* __restrict__ gCursor,
                           unsigned* __restrict__ bbuf) {
    __shared__ int cnt[NBKT];
    __shared__ int base[NBKT];
    for (int i = threadIdx.x; i < NBKT; i += 256) cnt[i] = 0;
    __syncthreads();
    const int4* s4 = (const int4*)src;
    const int4* d4 = (const int4*)dst;
    const float4* w4 = (const float4*)ew;
    int b4 = blockIdx.x * (TILE / 4);
    unsigned rec[16]; int bkt[16];
    #pragma unroll
    for (int j = 0; j < 4; j++) {
        int i4 = b4 + j * 256 + threadIdx.x;
        if (i4 < NE4) {
            int4 s = s4[i4]; int4 d = d4[i4]; float4 w = w4[i4];
            int b0 = d.x >> 6, b1 = d.y >> 6, b2 = d.z >> 6, b3 = d.w >> 6;
            bkt[4*j+0] = b0; bkt[4*j+1] = b1; bkt[4*j+2] = b2; bkt[4*j+3] = b3;
            rec[4*j+0] = (unsigned)s.x | ((unsigned)(d.x & 63) << 16) | ((unsigned)(w.x * 1023.f + 0.5f) << 22);
            rec[4*j+1] = (unsigned)s.y | ((unsigned)(d.y & 63) << 16) | ((unsigned)(w.y * 1023.f + 0.5f) << 22);
            rec[4*j+2] = (unsigned)s.z | ((unsigned)(d.z & 63) << 16) | ((unsigned)(w.z * 1023.f + 0.5f) << 22);
            rec[4*j+3] = (unsigned)s.w | ((unsigned)(d.w & 63) << 16) | ((unsigned)(w.w * 1023.f + 0.5f) << 22);
            atomicAdd(&cnt[b0], 1); atomicAdd(&cnt[b1], 1);
            atomicAdd(&cnt[b2], 1); atomicAdd(&cnt[b3], 1);
        } else {
            bkt[4*j+0] = -1; bkt[4*j+1] = -1; bkt[4*j+2] = -1; bkt[4*j+3] = -1;
        }
    }
    __syncthreads();
    for (int i = threadIdx.x; i < NBKT; i += 256)
        base[i] = cnt[i] ? (i << 11) + atomicAdd(&gCursor[i], cnt[i]) : 0;
    __syncthreads();
    #pragma unroll
    for (int j = 0; j < 16; j++) {
        if (bkt[j] >= 0) {
            int pos = atomicAdd(&base[bkt[j]], 1);
            if (pos < ((bkt[j] + 1) << 11)) bbuf[pos] = rec[j];   // overflow clamp (never in practice)
        }
    }
}

// ---------- per-bucket sort into final CSR; emits off + deg ----------
__global__ void k_bsort(const int* __restrict__ gCursor, const unsigned* __restrict__ bbuf,
                        int* __restrict__ off, int* __restrict__ deg,
                        unsigned* __restrict__ pairP) {
    int b = blockIdx.x;
    int st = b << 11;
    int ce = gCursor[b]; if (ce > BCAP) ce = BCAP;
    __shared__ unsigned sbuf[BCAP];   // 8KB
    __shared__ int h[64];
    __shared__ int cur[64];
    if (threadIdx.x < 64) h[threadIdx.x] = 0;
    __syncthreads();
    for (int i = threadIdx.x; i < ce; i += 256) {
        unsigned r = bbuf[st + i];
        sbuf[i] = r;
        atomicAdd(&h[(r >> 16) & 63], 1);
    }
    __syncthreads();
    if (threadIdx.x < 64) {
        int v = h[threadIdx.x];
        int inc = v;
        #pragma unroll
        for (int o = 1; o < 64; o <<= 1) {
            int tmp = __shfl_up(inc, o);
            if (threadIdx.x >= o) inc += tmp;
        }
        int exc = st + inc - v;
        cur[threadIdx.x] = exc;
        int n = b * 64 + threadIdx.x;
        if (n < NN) { off[n] = exc; deg[n] = v; }
    }
    __syncthreads();
    for (int i = threadIdx.x; i < ce; i += 256) {
        unsigned r = sbuf[i];
        int pos = atomicAdd(&cur[(r >> 16) & 63], 1);
        float w = (float)(r >> 22) * (1.f / 1023.f);
        unsigned hw = (unsigned)__half_as_ushort(__float2half(w));
        pairP[pos] = (r & 0xFFFFu) | (hw << 16);
    }
}

// ---------- fused node linear: wave = matrix (0=q,1=k,2=v,3=s), W col in VGPRs ----------
// LDS-staged x (16 nodes/tile, float4) with next-tile register prefetch; 4 indep accumulators.
// q written fp16 pre-scaled by log2(e)/8; kv row = [64 k-halfs][64 v-halfs]; agg f32.
__global__ __launch_bounds__(256, 4)
void k_linear(const float* __restrict__ xin,
              const float* __restrict__ Wq, const float* __restrict__ bq,
              const float* __restrict__ Wk, const float* __restrict__ bk,
              const float* __restrict__ Wv, const float* __restrict__ bv,
              const float* __restrict__ Ws, const float* __restrict__ bs,
              __half* __restrict__ qh, __half* __restrict__ kvh,
              float* __restrict__ agg) {
    int tid = threadIdx.x;
    int mat = tid >> 6, feat = tid & 63;
    const float* W = mat == 0 ? Wq : mat == 1 ? Wk : mat == 2 ? Wv : Ws;
    const float* b = mat == 0 ? bq : mat == 1 ? bk : mat == 2 ? bv : bs;

    float wcol[64];
    #pragma unroll
    for (int k = 0; k < 64; k++) wcol[k] = W[k * 64 + feat];
    float bias = b[feat];
    int kvoff = feat + (mat == 2 ? 64 : 0);

    __shared__ __align__(16) float sx[16 * 64];
    const float4* x4 = (const float4*)xin;

    int n0 = blockIdx.x * 16;
    if (n0 >= NN) return;
    float4 nxt = x4[n0 * 16 + tid];
    int stride = gridDim.x * 16;

    for (; n0 < NN; n0 += stride) {
        __syncthreads();
        ((float4*)sx)[tid] = nxt;
        __syncthreads();
        int n1 = n0 + stride;
        if (n1 < NN) nxt = x4[n1 * 16 + tid];   // prefetch next tile under compute
        for (int c = 0; c < 16; c++) {
            const float4* sxc = (const float4*)(sx + c * 64);
            float a0 = bias, a1 = 0.f, a2 = 0.f, a3 = 0.f;
            #pragma unroll
            for (int k4 = 0; k4 < 16; k4 += 4) {
                float4 v0 = sxc[k4 + 0], v1 = sxc[k4 + 1];
                float4 v2 = sxc[k4 + 2], v3 = sxc[k4 + 3];
                a0 = fmaf(v0.x, wcol[4 * k4 + 0], a0);
                a0 = fmaf(v0.y, wcol[4 * k4 + 1], a0);
                a0 = fmaf(v0.z, wcol[4 * k4 + 2], a0);
                a0 = fmaf(v0.w, wcol[4 * k4 + 3], a0);
                a1 = fmaf(v1.x, wcol[4 * k4 + 4], a1);
                a1 = fmaf(v1.y, wcol[4 * k4 + 5], a1);
                a1 = fmaf(v1.z, wcol[4 * k4 + 6], a1);
                a1 = fmaf(v1.w, wcol[4 * k4 + 7], a1);
                a2 = fmaf(v2.x, wcol[4 * k4 + 8], a2);
                a2 = fmaf(v2.y, wcol[4 * k4 + 9], a2);
                a2 = fmaf(v2.z, wcol[4 * k4 + 10], a2);
                a2 = fmaf(v2.w, wcol[4 * k4 + 11], a2);
                a3 = fmaf(v3.x, wcol[4 * k4 + 12], a3);
                a3 = fmaf(v3.y, wcol[4 * k4 + 13], a3);
                a3 = fmaf(v3.z, wcol[4 * k4 + 14], a3);
                a3 = fmaf(v3.w, wcol[4 * k4 + 15], a3);
            }
            float acc = (a0 + a1) + (a2 + a3);
            int nn = n0 + c;
            if (mat == 0)      qh[nn * 64 + feat] = __float2half(acc * QSCALE);
            else if (mat == 3) agg[nn * 64 + feat] = acc;
            else               kvh[nn * 128 + kvoff] = __float2half(acc);
        }
    }
}

// ---------- fused edge kernel: wave per dst node, 8-lane groups, fdot2, no-max softmax ----------
// stores relu(skip + attn) to outp[node row]
__global__ void k_edge(const unsigned* __restrict__ pairP, const int* __restrict__ off,
                       const int* __restrict__ deg,
                       const __half* __restrict__ qh, const uint4* __restrict__ kv16,
                       const float* __restrict__ We, const float* __restrict__ aggin,
                       float* __restrict__ outp) {
    long gid = (long)blockIdx.x * 256 + threadIdx.x;
    int n = (int)(gid >> 6);
    if (n >= NN) return;
    int lane = threadIdx.x & 63;
    int g = lane >> 3, l = lane & 7;   // 8 groups x 8 lanes

    const uint4* q4 = (const uint4*)qh;
    uint4 qu = q4[n * 8 + l];          // 8 fp16 q feats (pre-scaled by log2e/8)
    const float4* wp = (const float4*)(We + l * 8);
    float4 wa = wp[0], wb = wp[1];
    unsigned we01 = h2u(__floats2half2_rn(wa.x, wa.y));
    unsigned we23 = h2u(__floats2half2_rn(wa.z, wa.w));
    unsigned we45 = h2u(__floats2half2_rn(wb.x, wb.y));
    unsigned we67 = h2u(__floats2half2_rn(wb.z, wb.w));

    int st = off[n], dg = deg[n];

    float qwe = fdot2f(qu.x, we01, fdot2f(qu.y, we23,
                fdot2f(qu.z, we45, fdot2f(qu.w, we67, 0.f))));
    qwe += __shfl_xor(qwe, 1); qwe += __shfl_xor(qwe, 2); qwe += __shfl_xor(qwe, 4);

    float den = 0.f, sw = 0.f;
    float acc[8] = {0.f, 0.f, 0.f, 0.f, 0.f, 0.f, 0.f, 0.f};

    auto edge = [&](unsigned pr, uint4 kk, uint4 vv) {
        float w = __half2float(__ushort_as_half((unsigned short)(pr >> 16)));
        float tA = fdot2f(qu.x, kk.x, fdot2f(qu.y, kk.y, 0.f));
        float tB = fdot2f(qu.z, kk.z, fdot2f(qu.w, kk.w, 0.f));
        float t = tA + tB;
        t += __shfl_xor(t, 1); t += __shfl_xor(t, 2); t += __shfl_xor(t, 4);
        t = fmaf(w, qwe, t);
        float p = EXP2(t);            // shift-invariant softmax, |t| << 127
        den += p;
        sw = fmaf(p, w, sw);
        float2 v0 = __half22float2(__builtin_bit_cast(__half2, vv.x));
        float2 v1 = __half22float2(__builtin_bit_cast(__half2, vv.y));
        float2 v2 = __half22float2(__builtin_bit_cast(__half2, vv.z));
        float2 v3 = __half22float2(__builtin_bit_cast(__half2, vv.w));
        acc[0] = fmaf(p, v0.x, acc[0]); acc[1] = fmaf(p, v0.y, acc[1]);
        acc[2] = fmaf(p, v1.x, acc[2]); acc[3] = fmaf(p, v1.y, acc[3]);
        acc[4] = fmaf(p, v2.x, acc[4]); acc[5] = fmaf(p, v2.y, acc[5]);
        acc[6] = fmaf(p, v3.x, acc[6]); acc[7] = fmaf(p, v3.y, acc[7]);
    };

    int nfull = dg >> 3;
    if (nfull > 0) {
        unsigned prA = pairP[st + g];
        unsigned prB = (nfull > 1) ? pairP[st + 8 + g] : 0u;
        unsigned rowA = prA & 0xFFFFu;
        uint4 kkA = kv16[rowA * 16 + l];
        uint4 vvA = kv16[rowA * 16 + 8 + l];
        for (int i = 0; i + 1 < nfull; i++) {
            unsigned prC = (i + 2 < nfull) ? pairP[st + (i + 2) * 8 + g] : 0u;
            unsigned rowB = prB & 0xFFFFu;
            uint4 kkB = kv16[rowB * 16 + l];
            uint4 vvB = kv16[rowB * 16 + 8 + l];
            edge(prA, kkA, vvA);
            prA = prB; kkA = kkB; vvA = vvB; prB = prC;
        }
        edge(prA, kkA, vvA);
    }
    int tl = nfull * 8 + g;
    if (tl < dg) {
        unsigned pr = pairP[st + tl];
        unsigned row = pr & 0xFFFFu;
        uint4 kk = kv16[row * 16 + l];
        uint4 vv = kv16[row * 16 + 8 + l];
        edge(pr, kk, vv);
    }

    // merge the 8 group states (pure adds)
    #pragma unroll
    for (int o = 8; o <= 32; o <<= 1) {
        den += __shfl_xor(den, o);
        sw  += __shfl_xor(sw, o);
        #pragma unroll
        for (int j = 0; j < 8; j++) acc[j] += __shfl_xor(acc[j], o);
    }

    if (g == 0) {
        float inv = 1.f / fmaxf(den, 1e-16f);
        float swi = sw * inv;
        const float4* ain = (const float4*)(aggin + n * 64 + l * 8);
        float4 a0 = ain[0], a1 = ain[1];
        a0.x = fmaxf(fmaf(acc[0], inv, fmaf(swi, wa.x, a0.x)), 0.f);
        a0.y = fmaxf(fmaf(acc[1], inv, fmaf(swi, wa.y, a0.y)), 0.f);
        a0.z = fmaxf(fmaf(acc[2], inv, fmaf(swi, wa.z, a0.z)), 0.f);
        a0.w = fmaxf(fmaf(acc[3], inv, fmaf(swi, wa.w, a0.w)), 0.f);
        a1.x = fmaxf(fmaf(acc[4], inv, fmaf(swi, wb.x, a1.x)), 0.f);
        a1.y = fmaxf(fmaf(acc[5], inv, fmaf(swi, wb.y, a1.y)), 0.f);
        a1.z = fmaxf(fmaf(acc[6], inv, fmaf(swi, wb.z, a1.z)), 0.f);
        a1.w = fmaxf(fmaf(acc[7], inv, fmaf(swi, wb.w, a1.w)), 0.f);
        float4* ao = (float4*)(outp + n * 64 + l * 8);
        ao[0] = a0; ao[1] = a1;
    }
}

// ---------- pool + head: block per graph, batch is sorted ----------
__global__ void k_final(const float* __restrict__ h, const int* __restrict__ batch,
                        const float* __restrict__ Wl, const float* __restrict__ bl,
                        float* __restrict__ out) {
    int g = blockIdx.x;
    int tid = threadIdx.x;
    int lo = 0, hi = NN;
    while (lo < hi) { int mid = (lo + hi) >> 1; if (batch[mid] < g) lo = mid + 1; else hi = mid; }
    int s0 = lo;
    hi = NN;
    while (lo < hi) { int mid = (lo + hi) >> 1; if (batch[mid] < g + 1) lo = mid + 1; else hi = mid; }
    int s1 = lo;

    int sub = tid >> 6, lane = tid & 63;
    float a = 0.f;
    for (int n = s0 + sub; n < s1; n += 4) a += h[n * 64 + lane];   // h already relu'd
    __shared__ float sred[4][64];
    sred[sub][lane] = a;
    __syncthreads();
    if (tid < 64) {
        float p = (sred[0][tid] + sred[1][tid] + sred[2][tid] + sred[3][tid])
                  / fmaxf((float)(s1 - s0), 1.f);
        float a0 = p * Wl[tid * 2 + 0];
        float a1 = p * Wl[tid * 2 + 1];
        #pragma unroll
        for (int o = 1; o < 64; o <<= 1) { a0 += __shfl_xor(a0, o); a1 += __shfl_xor(a1, o); }
        if (tid == 0) { out[g * 2 + 0] = a0 + bl[0]; out[g * 2 + 1] = a1 + bl[1]; }
    }
}

extern "C" void kernel_launch(void* const* d_in, const int* in_sizes, int n_in,
                              void* d_out, int out_size, void* d_ws, size_t ws_size,
                              hipStream_t stream) {
    const float* x    = (const float*)d_in[0];
    const int*   ei   = (const int*)d_in[1];
    const float* ew   = (const float*)d_in[2];
    const int*   batch= (const int*)d_in[3];
    const float *Wq1 = (const float*)d_in[4],  *bq1 = (const float*)d_in[5],
                *Wk1 = (const float*)d_in[6],  *bk1 = (const float*)d_in[7],
                *Wv1 = (const float*)d_in[8],  *bv1 = (const float*)d_in[9],
                *We1 = (const float*)d_in[10], *Ws1 = (const float*)d_in[11],
                *bs1 = (const float*)d_in[12],
                *Wq2 = (const float*)d_in[13], *bq2 = (const float*)d_in[14],
                *Wk2 = (const float*)d_in[15], *bk2 = (const float*)d_in[16],
                *Wv2 = (const float*)d_in[17], *bv2 = (const float*)d_in[18],
                *We2 = (const float*)d_in[19], *Ws2 = (const float*)d_in[20],
                *bs2 = (const float*)d_in[21],
                *Wl  = (const float*)d_in[22], *bl  = (const float*)d_in[23];
    const int* src = ei;        // edge_index[0]
    const int* dst = ei + NE;   // edge_index[1]
    float* out = (float*)d_out;

    float* p = (float*)d_ws;
    float* agg1 = p; p += (size_t)NN * 64;
    float* agg2 = p; p += (size_t)NN * 64;
    __half* qh  = (__half*)p; p += (size_t)NN * 32;   // NN*64 halfs
    __half* kvh = (__half*)p; p += (size_t)NN * 64;   // NN*128 halfs
    unsigned* bbuf  = (unsigned*)p; p += (size_t)NBKT * BCAP;
    unsigned* pairP = (unsigned*)p; p += (size_t)NBKT * BCAP;
    int* gCursor = (int*)p; p += NBKT;
    int* off     = (int*)p; p += NN;
    int* deg     = (int*)p; p += NN;

    dim3 b256(256);
    int wgrid = (int)(((long)NN * 64 + 255) / 256);     // wave per node: 12500

    // ---- CSR build: zero cursors, multisplit scatter (fixed regions), per-bucket sort ----
    k_zero<<<4, b256, 0, stream>>>(gCursor);
    k_bscatter<<<NTB, b256, 0, stream>>>(src, dst, ew, gCursor, bbuf);
    k_bsort<<<NBKT, b256, 0, stream>>>(gCursor, bbuf, off, deg, pairP);

    // ---- layer 1 (k_edge stores relu'd h1 into agg1) ----
    k_linear<<<1024, b256, 0, stream>>>(x, Wq1, bq1, Wk1, bk1, Wv1, bv1, Ws1, bs1,
                                        qh, kvh, agg1);
    k_edge<<<wgrid, b256, 0, stream>>>(pairP, off, deg, qh, (const uint4*)kvh, We1,
                                       agg1, agg1);

    // ---- layer 2 ----
    k_linear<<<1024, b256, 0, stream>>>(agg1, Wq2, bq2, Wk2, bk2, Wv2, bv2, Ws2, bs2,
                                        qh, kvh, agg2);
    k_edge<<<wgrid, b256, 0, stream>>>(pairP, off, deg, qh, (const uint4*)kvh, We2,
                                       agg2, agg2);

    // ---- pool + head ----
    k_final<<<NG, b256, 0, stream>>>(agg2, batch, Wl, bl, out);
}